// Round 5
// baseline (693.069 us; speedup 1.0000x reference)
//
#include <hip/hip_runtime.h>

typedef __bf16 bf16x8 __attribute__((ext_vector_type(8)));
typedef float f32x4 __attribute__((ext_vector_type(4)));
typedef unsigned short ushort_t;

__device__ __forceinline__ ushort_t f2bf(float f) {
  unsigned int u = __float_as_uint(f);
  u += 0x7fffu + ((u >> 16) & 1u);
  return (ushort_t)(u >> 16);
}

// async global->LDS, 16 bytes per lane (dest = wave-uniform base + lane*16)
__device__ __forceinline__ void gl_lds16(const ushort_t* g, const char* l) {
  __builtin_amdgcn_global_load_lds(
      (const __attribute__((address_space(1))) void*)g,
      (__attribute__((address_space(3))) void*)l, 16, 0, 0);
}

__global__ __launch_bounds__(256) void fill_k(float* __restrict__ p, long n, float v) {
  long i = (long)blockIdx.x * 256 + threadIdx.x;
  if (i < n) p[i] = v;
}

// ---------------- batched transpose: fp32 Z x R x C  ->  bf16 Z x C x R ----
__global__ __launch_bounds__(256) void transpose_w(const float* __restrict__ in,
                                                   ushort_t* __restrict__ out,
                                                   int R, int C) {
  __shared__ float tile[32][33];
  const float* inb = in + (long)blockIdx.z * R * C;
  ushort_t* outb = out + (long)blockIdx.z * R * C;
  int r0 = blockIdx.x * 32, c0 = blockIdx.y * 32;
  int tx = threadIdx.x & 31, ty = threadIdx.x >> 5;
#pragma unroll
  for (int i = ty; i < 32; i += 8) tile[i][tx] = inb[(long)(r0 + i) * C + (c0 + tx)];
  __syncthreads();
#pragma unroll
  for (int i = ty; i < 32; i += 8) outb[(long)(c0 + i) * R + (r0 + tx)] = f2bf(tile[tx][i]);
}

// ---------------- layernorm: one row (D=1024) per 256-thread block ---------
__global__ __launch_bounds__(256) void ln_k(const float* __restrict__ x,
                                            const float* __restrict__ g,
                                            const float* __restrict__ b,
                                            float* __restrict__ outF,
                                            ushort_t* __restrict__ outU) {
  __shared__ float red[8];
  long row = blockIdx.x;
  int tid = threadIdx.x;
  float4 v = ((const float4*)(x + row * 1024))[tid];
  float s = v.x + v.y + v.z + v.w;
#pragma unroll
  for (int off = 32; off; off >>= 1) s += __shfl_xor(s, off);
  int w = tid >> 6;
  if ((tid & 63) == 0) red[w] = s;
  __syncthreads();
  float mean = (red[0] + red[1] + red[2] + red[3]) * (1.0f / 1024.0f);
  float dx = v.x - mean, dy = v.y - mean, dz = v.z - mean, dw = v.w - mean;
  float s2 = dx * dx + dy * dy + dz * dz + dw * dw;
#pragma unroll
  for (int off = 32; off; off >>= 1) s2 += __shfl_xor(s2, off);
  if ((tid & 63) == 0) red[4 + w] = s2;
  __syncthreads();
  float var = (red[4] + red[5] + red[6] + red[7]) * (1.0f / 1024.0f);
  float rstd = rsqrtf(var + 1e-5f);
  int c = tid * 4;
  float o0 = dx * rstd * g[c + 0] + b[c + 0];
  float o1 = dy * rstd * g[c + 1] + b[c + 1];
  float o2 = dz * rstd * g[c + 2] + b[c + 2];
  float o3 = dw * rstd * g[c + 3] + b[c + 3];
  ((float4*)(outF + row * 1024))[tid] = make_float4(o0, o1, o2, o3);
  ushort4 u;
  u.x = f2bf(o0); u.y = f2bf(o1); u.z = f2bf(o2); u.w = f2bf(o3);
  ((ushort4*)(outU + row * 1024))[tid] = u;
}

// ---------------- 256x256 8-wave 4-phase bf16 GEMM (BK=64) -----------------
// C(MxN) = A(MxK) * Bt(NxK)^T, fp32 accum. 2 LDS buffers x (A 32KB + B 32KB).
// Per K-tile: ph0 {stage next tile 8x gl_lds | vmcnt(8) | barrier | ds_read
// A0-3,B0-1 | MFMA quad | barrier}; ph1 {ds_read B2-3 | MFMA}; ph2 {ds_read
// A4-7 | MFMA}; ph3 {MFMA}. Counted vmcnt (T4), setprio (T5), XOR swizzle
// (T2, phys 16B-slot = log ^ (row&7), both-sides), XCD swizzle (T1).
// Epilogues: 2: fp32 acc+bias[col]+res   3: bf16 relu(acc+bias[col])
//            4: fused QKV -> q[b,h,t,e], k[b,h,t,e], v[b,h,e,t]
template <int EPI>
__global__ __launch_bounds__(512, 2) void gemm256(const ushort_t* __restrict__ A,
                                                  const ushort_t* __restrict__ Bt,
                                                  int M, int N, int K, int NBC,
                                                  const float* __restrict__ bias,
                                                  const float* res, float* outF,
                                                  ushort_t* __restrict__ outU,
                                                  ushort_t* __restrict__ outU2,
                                                  ushort_t* __restrict__ outU3) {
  __shared__ __align__(16) char lds[131072];
  const int tid = threadIdx.x;
  const int lane = tid & 63;
  const int w = tid >> 6;            // 0..7
  const int wr = w >> 2, wc = w & 3; // 2 x 4 wave grid
  const int g = lane >> 4, lr = lane & 15;
  // T1: bijective XCD swizzle (gridDim.x % 8 == 0)
  const int cpx = gridDim.x >> 3;
  const int wg = (blockIdx.x & 7) * cpx + (blockIdx.x >> 3);
  const long m0 = (long)(wg / NBC) * 256;
  const long n0 = (long)(wg % NBC) * 256;
  // staging source (pre-swizzled so linear gl_lds dest yields swizzled LDS)
  const int srow = tid >> 3;                  // 0..63 within an 8KB issue
  const int sslot = (tid & 7) ^ (srow & 7);   // logical 16B slot to fetch
  const ushort_t* sA = A + (m0 + srow) * (long)K + sslot * 8;
  const ushort_t* sB = Bt + (n0 + srow) * (long)K + sslot * 8;
  const int dA = tid * 16;
  const int dB = 32768 + tid * 16;
  // ds_read bases: row-major [256][64]x2B, phys slot = log ^ (row&7)
  const int abase = (wr * 128 + lr) * 128;
  const int bbase = 32768 + (wc * 64 + lr) * 128;
  const int s0 = g ^ (lr & 7);         // ks=0: logical slot g
  const int s1 = (4 + g) ^ (lr & 7);   // ks=1: logical slot 4+g
  const int NT = K >> 6;

  f32x4 acc[8][4] = {};

  // prologue: stage tile 0 into buf 0
#pragma unroll
  for (int j = 0; j < 4; ++j) gl_lds16(sA + (long)j * 64 * K, lds + j * 8192 + dA);
#pragma unroll
  for (int j = 0; j < 4; ++j) gl_lds16(sB + (long)j * 64 * K, lds + j * 8192 + dB);

  bf16x8 aR[4][2], bR[4][2];
  int c = 0;
  for (int t = 0; t < NT; ++t) {
    const char* rb = lds + c;
    // ---- ph0: stage t+1, counted vmcnt, validity barrier, quad(mf0-3,nf0-1)
    if (t + 1 < NT) {
      const long ko = (long)(t + 1) * 64;
      const int d = c ^ 65536;
#pragma unroll
      for (int j = 0; j < 4; ++j) gl_lds16(sA + ko + (long)j * 64 * K, lds + d + j * 8192 + dA);
#pragma unroll
      for (int j = 0; j < 4; ++j) gl_lds16(sB + ko + (long)j * 64 * K, lds + d + j * 8192 + dB);
      asm volatile("s_waitcnt vmcnt(8)" ::: "memory");   // tile t landed; 8 in flight
    } else {
      asm volatile("s_waitcnt vmcnt(0)" ::: "memory");
    }
    __builtin_amdgcn_s_barrier();
    __builtin_amdgcn_sched_barrier(0);   // keep ds_reads after validity barrier
#pragma unroll
    for (int mf = 0; mf < 4; ++mf) {
      aR[mf][0] = *(const bf16x8*)(rb + abase + mf * 2048 + s0 * 16);
      aR[mf][1] = *(const bf16x8*)(rb + abase + mf * 2048 + s1 * 16);
    }
#pragma unroll
    for (int nf = 0; nf < 2; ++nf) {
      bR[nf][0] = *(const bf16x8*)(rb + bbase + nf * 2048 + s0 * 16);
      bR[nf][1] = *(const bf16x8*)(rb + bbase + nf * 2048 + s1 * 16);
    }
    __builtin_amdgcn_s_setprio(1);
#pragma unroll
    for (int mf = 0; mf < 4; ++mf)
#pragma unroll
      for (int nf = 0; nf < 2; ++nf) {
        acc[mf][nf] = __builtin_amdgcn_mfma_f32_16x16x32_bf16(aR[mf][0], bR[nf][0], acc[mf][nf], 0, 0, 0);
        acc[mf][nf] = __builtin_amdgcn_mfma_f32_16x16x32_bf16(aR[mf][1], bR[nf][1], acc[mf][nf], 0, 0, 0);
      }
    __builtin_amdgcn_s_setprio(0);
    __builtin_amdgcn_s_barrier();
    // ---- ph1: read B2-3, quad(mf0-3, nf2-3) --------------------------------
#pragma unroll
    for (int nf = 2; nf < 4; ++nf) {
      bR[nf][0] = *(const bf16x8*)(rb + bbase + nf * 2048 + s0 * 16);
      bR[nf][1] = *(const bf16x8*)(rb + bbase + nf * 2048 + s1 * 16);
    }
    __builtin_amdgcn_s_setprio(1);
#pragma unroll
    for (int mf = 0; mf < 4; ++mf)
#pragma unroll
      for (int nf = 2; nf < 4; ++nf) {
        acc[mf][nf] = __builtin_amdgcn_mfma_f32_16x16x32_bf16(aR[mf][0], bR[nf][0], acc[mf][nf], 0, 0, 0);
        acc[mf][nf] = __builtin_amdgcn_mfma_f32_16x16x32_bf16(aR[mf][1], bR[nf][1], acc[mf][nf], 0, 0, 0);
      }
    __builtin_amdgcn_s_setprio(0);
    __builtin_amdgcn_s_barrier();
    // ---- ph2: read A4-7 (overwrite aR), quad(mf4-7, nf2-3) -----------------
#pragma unroll
    for (int mf = 0; mf < 4; ++mf) {
      aR[mf][0] = *(const bf16x8*)(rb + abase + (4 + mf) * 2048 + s0 * 16);
      aR[mf][1] = *(const bf16x8*)(rb + abase + (4 + mf) * 2048 + s1 * 16);
    }
    __builtin_amdgcn_s_setprio(1);
#pragma unroll
    for (int mf = 0; mf < 4; ++mf)
#pragma unroll
      for (int nf = 2; nf < 4; ++nf) {
        acc[4 + mf][nf] = __builtin_amdgcn_mfma_f32_16x16x32_bf16(aR[mf][0], bR[nf][0], acc[4 + mf][nf], 0, 0, 0);
        acc[4 + mf][nf] = __builtin_amdgcn_mfma_f32_16x16x32_bf16(aR[mf][1], bR[nf][1], acc[4 + mf][nf], 0, 0, 0);
      }
    __builtin_amdgcn_s_setprio(0);
    __builtin_amdgcn_s_barrier();
    // ---- ph3: quad(mf4-7, nf0-1) -------------------------------------------
    __builtin_amdgcn_s_setprio(1);
#pragma unroll
    for (int mf = 0; mf < 4; ++mf)
#pragma unroll
      for (int nf = 0; nf < 2; ++nf) {
        acc[4 + mf][nf] = __builtin_amdgcn_mfma_f32_16x16x32_bf16(aR[mf][0], bR[nf][0], acc[4 + mf][nf], 0, 0, 0);
        acc[4 + mf][nf] = __builtin_amdgcn_mfma_f32_16x16x32_bf16(aR[mf][1], bR[nf][1], acc[4 + mf][nf], 0, 0, 0);
      }
    __builtin_amdgcn_s_setprio(0);
    __builtin_amdgcn_s_barrier();
    c ^= 65536;
  }

  // epilogue: C/D frag layout col=lr, row=g*4+r  [m89]
#pragma unroll
  for (int mf = 0; mf < 8; ++mf)
#pragma unroll
    for (int nf = 0; nf < 4; ++nf)
#pragma unroll
      for (int r = 0; r < 4; ++r) {
        long row = m0 + wr * 128 + mf * 16 + g * 4 + r;
        long col = n0 + wc * 64 + nf * 16 + lr;
        float v = acc[mf][nf][r];
        if constexpr (EPI == 2) {
          long i = row * N + col;
          outF[i] = v + bias[col] + res[i];
        } else if constexpr (EPI == 3) {
          outU[row * N + col] = f2bf(fmaxf(v + bias[col], 0.0f));
        } else {  // EPI 4: fused QKV
          long bb2 = row >> 8, tt = row & 255;
          long p = col >> 10, cc = col & 1023, hh = cc >> 6, e = cc & 63;
          if (p == 0)
            outU[(((bb2 * 16 + hh) * 256 + tt) << 6) + e] = f2bf(v);
          else if (p == 1)
            outU2[(((bb2 * 16 + hh) * 256 + tt) << 6) + e] = f2bf(v);
          else
            outU3[(((bb2 * 16 + hh) * 64 + e) << 8) + tt] = f2bf(v);
        }
      }
}

// ---------------- flash attention: 1 wave per (64 q rows, b, h) ------------
// q,k: [b,h,t,e] bf16; vt: [b,h,e,t] bf16; out: [b,t,h*64+e] bf16
__global__ __launch_bounds__(64) void attn_k(const ushort_t* __restrict__ q,
                                             const ushort_t* __restrict__ k,
                                             const ushort_t* __restrict__ vt,
                                             ushort_t* __restrict__ ao) {
  __shared__ __align__(16) ushort_t Ps[64][40];
  const int lane = threadIdx.x;
  const int g = lane >> 4, lr = lane & 15;
  const int blk = blockIdx.x;
  const int q4 = blk & 3;
  const int bh = blk >> 2;
  const int bb = bh >> 4, hh = bh & 15;
  const int q0 = q4 * 64;
  const ushort_t* qb = q + (long)bh * 256 * 64;
  const ushort_t* kb = k + (long)bh * 256 * 64;
  const ushort_t* vb = vt + (long)bh * 64 * 256;
  bf16x8 qf[4][2];
#pragma unroll
  for (int m = 0; m < 4; m++)
#pragma unroll
    for (int ks = 0; ks < 2; ks++)
      qf[m][ks] = *(const bf16x8*)(qb + (q0 + m * 16 + lr) * 64 + ks * 32 + g * 8);
  f32x4 o[4][4] = {};
  float mrow[4][4], lrow[4][4];
#pragma unroll
  for (int m = 0; m < 4; m++)
#pragma unroll
    for (int r = 0; r < 4; r++) { mrow[m][r] = -__builtin_inff(); lrow[m][r] = 0.0f; }
  const float scale = 0.03125f;  // 1024^-0.5
  const int nkb = q0 / 32 + 2;
  for (int kbk = 0; kbk < nkb; kbk++) {
    f32x4 s[4][2] = {};
#pragma unroll
    for (int ks = 0; ks < 2; ks++) {
      bf16x8 kf[2];
#pragma unroll
      for (int n = 0; n < 2; n++)
        kf[n] = *(const bf16x8*)(kb + (kbk * 32 + n * 16 + lr) * 64 + ks * 32 + g * 8);
#pragma unroll
      for (int m = 0; m < 4; m++)
#pragma unroll
        for (int n = 0; n < 2; n++)
          s[m][n] = __builtin_amdgcn_mfma_f32_16x16x32_bf16(qf[m][ks], kf[n], s[m][n], 0, 0, 0);
    }
#pragma unroll
    for (int m = 0; m < 4; m++)
#pragma unroll
      for (int n = 0; n < 2; n++)
#pragma unroll
        for (int r = 0; r < 4; r++) {
          int row = q0 + m * 16 + g * 4 + r;
          int col = kbk * 32 + n * 16 + lr;
          float v = s[m][n][r] * scale;
          s[m][n][r] = (col <= row) ? v : -1e30f;
        }
#pragma unroll
    for (int m = 0; m < 4; m++)
#pragma unroll
      for (int r = 0; r < 4; r++) {
        float mx = fmaxf(s[m][0][r], s[m][1][r]);
#pragma unroll
        for (int off = 8; off; off >>= 1) mx = fmaxf(mx, __shfl_xor(mx, off));
        float mn = fmaxf(mrow[m][r], mx);
        float alpha = __expf(mrow[m][r] - mn);
        mrow[m][r] = mn;
        float rs = 0.0f;
#pragma unroll
        for (int n = 0; n < 2; n++) {
          float p = __expf(s[m][n][r] - mn);
          s[m][n][r] = p;
          rs += p;
        }
#pragma unroll
        for (int off = 8; off; off >>= 1) rs += __shfl_xor(rs, off);
        lrow[m][r] = lrow[m][r] * alpha + rs;
#pragma unroll
        for (int n = 0; n < 4; n++) o[m][n][r] *= alpha;
      }
#pragma unroll
    for (int m = 0; m < 4; m++)
#pragma unroll
      for (int n = 0; n < 2; n++)
#pragma unroll
        for (int r = 0; r < 4; r++)
          Ps[m * 16 + g * 4 + r][n * 16 + lr] = f2bf(s[m][n][r]);
    __syncthreads();
    bf16x8 vf[4];
#pragma unroll
    for (int n = 0; n < 4; n++)
      vf[n] = *(const bf16x8*)(vb + (n * 16 + lr) * 256 + kbk * 32 + g * 8);
#pragma unroll
    for (int m = 0; m < 4; m++) {
      bf16x8 pa = *(const bf16x8*)&Ps[m * 16 + lr][g * 8];
#pragma unroll
      for (int n = 0; n < 4; n++)
        o[m][n] = __builtin_amdgcn_mfma_f32_16x16x32_bf16(pa, vf[n], o[m][n], 0, 0, 0);
    }
    __syncthreads();
  }
#pragma unroll
  for (int m = 0; m < 4; m++)
#pragma unroll
    for (int r = 0; r < 4; r++) {
      float inv = 1.0f / lrow[m][r];
      long t = q0 + m * 16 + g * 4 + r;
#pragma unroll
      for (int n = 0; n < 4; n++) {
        long e = n * 16 + lr;
        ao[((long)bb * 256 + t) * 1024 + hh * 64 + e] = f2bf(o[m][n][r] * inv);
      }
    }
}

// ---------------- launch ---------------------------------------------------
// Workspace map (MB offsets, 184 MB): wqt@0 wkt@2 wvt@4 (contiguous N=3072
// fused B^T) wpt@6 w1t@8 w2t@16; hb@24 (bf16 h / h2); qbf@56 kbf@88 vtb@120
// atb@152; ff1 aliases @56. fp32 residual stream lives IN d_out.
extern "C" void kernel_launch(void* const* d_in, const int* in_sizes, int n_in,
                              void* d_out, int out_size, void* d_ws, size_t ws_size,
                              hipStream_t stream) {
  const float* x     = (const float*)d_in[0];
  const float* ln1g  = (const float*)d_in[1];
  const float* ln1b  = (const float*)d_in[2];
  const float* Wq    = (const float*)d_in[3];
  const float* Wk    = (const float*)d_in[4];
  const float* Wv    = (const float*)d_in[5];
  const float* Wproj = (const float*)d_in[6];
  const float* bproj = (const float*)d_in[7];
  const float* ln2g  = (const float*)d_in[8];
  const float* ln2b  = (const float*)d_in[9];
  const float* W1    = (const float*)d_in[10];
  const float* b1    = (const float*)d_in[11];
  const float* W2    = (const float*)d_in[12];
  const float* b2    = (const float*)d_in[13];

  const long NEED = 184L << 20;
  if (ws_size < (size_t)NEED) {
    fill_k<<<(out_size + 255) / 256, 256, 0, stream>>>((float*)d_out, out_size,
                                                       (float)(ws_size >> 20));
    return;
  }

  char* ws = (char*)d_ws;
  const long MB = 1 << 20;
  ushort_t* wqt = (ushort_t*)(ws + 0 * MB);   // [0,6MB) = fused QKV B^T, N=3072
  ushort_t* wkt = (ushort_t*)(ws + 2 * MB);
  ushort_t* wvt = (ushort_t*)(ws + 4 * MB);
  ushort_t* wpt = (ushort_t*)(ws + 6 * MB);
  ushort_t* w1t = (ushort_t*)(ws + 8 * MB);
  ushort_t* w2t = (ushort_t*)(ws + 16 * MB);
  ushort_t* hb  = (ushort_t*)(ws + 24 * MB);
  ushort_t* qbf = (ushort_t*)(ws + 56 * MB);
  ushort_t* kbf = (ushort_t*)(ws + 88 * MB);
  ushort_t* vtb = (ushort_t*)(ws + 120 * MB);
  ushort_t* atb = (ushort_t*)(ws + 152 * MB);
  ushort_t* ff1 = (ushort_t*)(ws + 56 * MB);
  float*    yf  = (float*)d_out;

  transpose_w<<<dim3(32, 2, 16), 256, 0, stream>>>(Wq, wqt, 1024, 64);
  transpose_w<<<dim3(32, 2, 16), 256, 0, stream>>>(Wk, wkt, 1024, 64);
  transpose_w<<<dim3(32, 2, 16), 256, 0, stream>>>(Wv, wvt, 1024, 64);
  transpose_w<<<dim3(32, 32, 1), 256, 0, stream>>>(Wproj, wpt, 1024, 1024);
  transpose_w<<<dim3(32, 128, 1), 256, 0, stream>>>(W1, w1t, 1024, 4096);
  transpose_w<<<dim3(128, 32, 1), 256, 0, stream>>>(W2, w2t, 4096, 1024);

  ln_k<<<16384, 256, 0, stream>>>(x, ln1g, ln1b, yf, hb);
  // fused q/k/v projection (M=16384, N=3072, K=1024; grid 64x12=768)
  gemm256<4><<<768, 512, 0, stream>>>(hb, wqt, 16384, 3072, 1024, 12,
                                      nullptr, nullptr, nullptr, qbf, kbf, vtb);
  attn_k<<<4096, 64, 0, stream>>>(qbf, kbf, vtb, atb);
  // y = h + attn @ Wproj + bproj
  gemm256<2><<<256, 512, 0, stream>>>(atb, wpt, 16384, 1024, 1024, 4,
                                      bproj, yf, yf, nullptr, nullptr, nullptr);
  ln_k<<<16384, 256, 0, stream>>>(yf, ln2g, ln2b, yf, hb);
  // ff1 = relu(h2 @ W1 + b1)  (N=4096; grid 64x16=1024)
  gemm256<3><<<1024, 512, 0, stream>>>(hb, w1t, 16384, 4096, 1024, 16,
                                       b1, nullptr, nullptr, ff1, nullptr, nullptr);
  // out = h2 + ff1 @ W2 + b2  (K=4096)
  gemm256<2><<<256, 512, 0, stream>>>(ff1, w2t, 16384, 1024, 4096, 4,
                                      b2, yf, yf, nullptr, nullptr, nullptr);
}

// Round 6
// 687.047 us; speedup vs baseline: 1.0088x; 1.0088x over previous
//
#include <hip/hip_runtime.h>

typedef __bf16 bf16x8 __attribute__((ext_vector_type(8)));
typedef float f32x4 __attribute__((ext_vector_type(4)));
typedef unsigned short ushort_t;

__device__ __forceinline__ ushort_t f2bf(float f) {
  unsigned int u = __float_as_uint(f);
  u += 0x7fffu + ((u >> 16) & 1u);
  return (ushort_t)(u >> 16);
}

// async global->LDS, 16 bytes per lane (dest = wave-uniform base + lane*16)
__device__ __forceinline__ void gl_lds16(const ushort_t* g, const char* l) {
  __builtin_amdgcn_global_load_lds(
      (const __attribute__((address_space(1))) void*)g,
      (__attribute__((address_space(3))) void*)l, 16, 0, 0);
}

__global__ __launch_bounds__(256) void fill_k(float* __restrict__ p, long n, float v) {
  long i = (long)blockIdx.x * 256 + threadIdx.x;
  if (i < n) p[i] = v;
}

// ---------------- batched transpose: fp32 Z x R x C  ->  bf16 Z x C x R ----
__global__ __launch_bounds__(256) void transpose_w(const float* __restrict__ in,
                                                   ushort_t* __restrict__ out,
                                                   int R, int C) {
  __shared__ float tile[32][33];
  const float* inb = in + (long)blockIdx.z * R * C;
  ushort_t* outb = out + (long)blockIdx.z * R * C;
  int r0 = blockIdx.x * 32, c0 = blockIdx.y * 32;
  int tx = threadIdx.x & 31, ty = threadIdx.x >> 5;
#pragma unroll
  for (int i = ty; i < 32; i += 8) tile[i][tx] = inb[(long)(r0 + i) * C + (c0 + tx)];
  __syncthreads();
#pragma unroll
  for (int i = ty; i < 32; i += 8) outb[(long)(c0 + i) * R + (r0 + tx)] = f2bf(tile[tx][i]);
}

// ---------------- layernorm: one row (D=1024) per 256-thread block ---------
__global__ __launch_bounds__(256) void ln_k(const float* __restrict__ x,
                                            const float* __restrict__ g,
                                            const float* __restrict__ b,
                                            float* __restrict__ outF,
                                            ushort_t* __restrict__ outU) {
  __shared__ float red[8];
  long row = blockIdx.x;
  int tid = threadIdx.x;
  float4 v = ((const float4*)(x + row * 1024))[tid];
  float s = v.x + v.y + v.z + v.w;
#pragma unroll
  for (int off = 32; off; off >>= 1) s += __shfl_xor(s, off);
  int w = tid >> 6;
  if ((tid & 63) == 0) red[w] = s;
  __syncthreads();
  float mean = (red[0] + red[1] + red[2] + red[3]) * (1.0f / 1024.0f);
  float dx = v.x - mean, dy = v.y - mean, dz = v.z - mean, dw = v.w - mean;
  float s2 = dx * dx + dy * dy + dz * dz + dw * dw;
#pragma unroll
  for (int off = 32; off; off >>= 1) s2 += __shfl_xor(s2, off);
  if ((tid & 63) == 0) red[4 + w] = s2;
  __syncthreads();
  float var = (red[4] + red[5] + red[6] + red[7]) * (1.0f / 1024.0f);
  float rstd = rsqrtf(var + 1e-5f);
  int c = tid * 4;
  float o0 = dx * rstd * g[c + 0] + b[c + 0];
  float o1 = dy * rstd * g[c + 1] + b[c + 1];
  float o2 = dz * rstd * g[c + 2] + b[c + 2];
  float o3 = dw * rstd * g[c + 3] + b[c + 3];
  ((float4*)(outF + row * 1024))[tid] = make_float4(o0, o1, o2, o3);
  ushort4 u;
  u.x = f2bf(o0); u.y = f2bf(o1); u.z = f2bf(o2); u.w = f2bf(o3);
  ((ushort4*)(outU + row * 1024))[tid] = u;
}

// ---------------- 256x256 8-wave 8-phase bf16 GEMM (BK=64, m201 rhythm) ----
// C(MxN) = A(MxK) * Bt(NxK)^T, fp32 accum. LDS: 2 dbuf x (A 32KB + B 32KB).
// Half-tile = 128 rows x 64 k = 16KB = 2 gl_lds issues. Per iteration
// (tiles t even -> buf0, t+1 -> buf1), 8 phases; each phase:
//   {ds_read subtile | stage half-tile} -> barrier -> lgkm(0)+sched_barrier
//   -> setprio(1) 16 MFMA setprio(0) -> barrier.
// Stage slots: ph1:A1(t+1) ph3:B0(t+2) ph4:B1+A0(t+2) ph5:A1(t+2)
//              ph7:B0(t+3) ph8:B1+A0(t+3).  vmcnt(6) at END of ph4/ph8 only.
// Safety: B-halves of a buffer are fully read after Q2's barrier, A-halves
// after Q3's; Q4/Q8 are register-only. Swizzle: phys 16B slot = log^(row&7),
// both-sides (pre-swizzled global source + swizzled ds_read). XCD swizzle T1.
// Epilogues: 2: fp32 acc+bias[col]+res   3: bf16 relu(acc+bias[col])
//            4: fused QKV -> q[b,h,t,e], k[b,h,t,e], v[b,h,e,t]
template <int EPI>
__global__ __launch_bounds__(512, 2) void gemm256(const ushort_t* __restrict__ A,
                                                  const ushort_t* __restrict__ Bt,
                                                  int M, int N, int K, int NBC,
                                                  const float* __restrict__ bias,
                                                  const float* res, float* outF,
                                                  ushort_t* __restrict__ outU,
                                                  ushort_t* __restrict__ outU2,
                                                  ushort_t* __restrict__ outU3) {
  __shared__ __align__(16) char lds[131072];
  const int tid = threadIdx.x;
  const int lane = tid & 63;
  const int w = tid >> 6;            // 0..7
  const int wr = w >> 2, wc = w & 3; // 2 x 4 wave grid
  const int g = lane >> 4, lr = lane & 15;
  const int cpx = gridDim.x >> 3;
  const int wg = (blockIdx.x & 7) * cpx + (blockIdx.x >> 3);
  const long m0 = (long)(wg / NBC) * 256;
  const long n0 = (long)(wg % NBC) * 256;
  // staging source (pre-swizzled so linear gl_lds dest yields swizzled LDS)
  const int srow = tid >> 3;                  // 0..63 within an 8KB issue
  const int sslot = (tid & 7) ^ (srow & 7);   // logical 16B slot to fetch
  const ushort_t* sA = A + (m0 + srow) * (long)K + sslot * 8;
  const ushort_t* sB = Bt + (n0 + srow) * (long)K + sslot * 8;
  const int dA = tid * 16;
  const int dB = 32768 + tid * 16;
  // ds_read bases: row-major [256][64]x2B per region, phys slot = log^(row&7)
  const int abase = (wr * 128 + lr) * 128;
  const int bbase = 32768 + (wc * 64 + lr) * 128;
  const int s0 = g ^ (lr & 7);         // ks=0: logical slot g
  const int s1 = (4 + g) ^ (lr & 7);   // ks=1: logical slot 4+g
  const int NT = K >> 6;

  f32x4 acc[8][4] = {};
  bf16x8 aR[4][2], bR[4][2];
  const char* rb;

#define STAGE_A(tile, half) do {                                          \
    const long _ko = (long)(tile) * 64;                                   \
    char* _d = lds + (((tile) & 1) << 16) + ((half) << 14) + dA;          \
    gl_lds16(sA + _ko + (long)(2 * (half)) * 64 * K, _d);                 \
    gl_lds16(sA + _ko + (long)(2 * (half) + 1) * 64 * K, _d + 8192);      \
  } while (0)
#define STAGE_B(tile, half) do {                                          \
    const long _ko = (long)(tile) * 64;                                   \
    char* _d = lds + (((tile) & 1) << 16) + ((half) << 14) + dB;          \
    gl_lds16(sB + _ko + (long)(2 * (half)) * 64 * K, _d);                 \
    gl_lds16(sB + _ko + (long)(2 * (half) + 1) * 64 * K, _d + 8192);      \
  } while (0)
#define RD_A(base_mf) do {                                                \
    _Pragma("unroll") for (int mf = 0; mf < 4; ++mf) {                    \
      aR[mf][0] = *(const bf16x8*)(rb + abase + ((base_mf) + mf) * 2048 + s0 * 16); \
      aR[mf][1] = *(const bf16x8*)(rb + abase + ((base_mf) + mf) * 2048 + s1 * 16); \
    } } while (0)
#define RD_B2(base_nf) do {                                               \
    _Pragma("unroll") for (int nf = 0; nf < 2; ++nf) {                    \
      bR[(base_nf) + nf][0] = *(const bf16x8*)(rb + bbase + ((base_nf) + nf) * 2048 + s0 * 16); \
      bR[(base_nf) + nf][1] = *(const bf16x8*)(rb + bbase + ((base_nf) + nf) * 2048 + s1 * 16); \
    } } while (0)
#define QUAD(MB, NB) do {                                                 \
    __builtin_amdgcn_s_setprio(1);                                        \
    _Pragma("unroll") for (int mf = 0; mf < 4; ++mf)                      \
      _Pragma("unroll") for (int nf = 0; nf < 2; ++nf) {                  \
        acc[(MB) + mf][(NB) + nf] = __builtin_amdgcn_mfma_f32_16x16x32_bf16(aR[mf][0], bR[(NB) + nf][0], acc[(MB) + mf][(NB) + nf], 0, 0, 0); \
        acc[(MB) + mf][(NB) + nf] = __builtin_amdgcn_mfma_f32_16x16x32_bf16(aR[mf][1], bR[(NB) + nf][1], acc[(MB) + mf][(NB) + nf], 0, 0, 0); \
      }                                                                   \
    __builtin_amdgcn_s_setprio(0); } while (0)
#define LGKM0 do {                                                        \
    asm volatile("s_waitcnt lgkmcnt(0)" ::: "memory");                    \
    __builtin_amdgcn_sched_barrier(0); } while (0)

  // ---- prologue: 7 half-tiles, oldest-first; drain tile 0 (8 loads) ----
  STAGE_B(0, 0); STAGE_B(0, 1); STAGE_A(0, 0); STAGE_A(0, 1);
  STAGE_B(1, 0); STAGE_B(1, 1); STAGE_A(1, 0);
  asm volatile("s_waitcnt vmcnt(6)" ::: "memory");
  __builtin_amdgcn_s_barrier();

  for (int t = 0; t < NT; t += 2) {
    const bool s2 = (t + 2 < NT), s3 = (t + 3 < NT);
    // ===================== tile t (buf0) =====================
    rb = lds;
    // ---- ph1: Q1(mf0-3,nf0-1); reads A0-3,B0-1; stage A1(t+1)
    RD_A(0);
    RD_B2(0);
    STAGE_A(t + 1, 1);
    asm volatile("s_waitcnt lgkmcnt(8)" ::: "memory");
    __builtin_amdgcn_s_barrier();
    LGKM0;
    QUAD(0, 0);
    __builtin_amdgcn_s_barrier();
    // ---- ph2: Q2(mf0-3,nf2-3); reads B2-3
    RD_B2(2);
    __builtin_amdgcn_s_barrier();
    LGKM0;
    QUAD(0, 2);
    __builtin_amdgcn_s_barrier();
    // ---- ph3: Q3(mf4-7,nf2-3); reads A4-7; stage B0(t+2)
    if (s2) STAGE_B(t + 2, 0);
    RD_A(4);
    __builtin_amdgcn_s_barrier();
    LGKM0;
    QUAD(4, 2);
    __builtin_amdgcn_s_barrier();
    // ---- ph4: Q4(mf4-7,nf0-1); register-only; stage B1+A0(t+2); vmcnt
    if (s2) { STAGE_B(t + 2, 1); STAGE_A(t + 2, 0); }
    __builtin_amdgcn_s_barrier();
    QUAD(4, 0);
    if (s2) asm volatile("s_waitcnt vmcnt(6)" ::: "memory");
    else    asm volatile("s_waitcnt vmcnt(0)" ::: "memory");
    __builtin_amdgcn_s_barrier();
    // ===================== tile t+1 (buf1) =====================
    rb = lds + 65536;
    // ---- ph5: Q1; reads A0-3,B0-1; stage A1(t+2)
    RD_A(0);
    RD_B2(0);
    if (s2) STAGE_A(t + 2, 1);
    asm volatile("s_waitcnt lgkmcnt(8)" ::: "memory");
    __builtin_amdgcn_s_barrier();
    LGKM0;
    QUAD(0, 0);
    __builtin_amdgcn_s_barrier();
    // ---- ph6: Q2; reads B2-3
    RD_B2(2);
    __builtin_amdgcn_s_barrier();
    LGKM0;
    QUAD(0, 2);
    __builtin_amdgcn_s_barrier();
    // ---- ph7: Q3; reads A4-7; stage B0(t+3)
    if (s3) STAGE_B(t + 3, 0);
    RD_A(4);
    __builtin_amdgcn_s_barrier();
    LGKM0;
    QUAD(4, 2);
    __builtin_amdgcn_s_barrier();
    // ---- ph8: Q4; register-only; stage B1+A0(t+3); vmcnt
    if (s3) { STAGE_B(t + 3, 1); STAGE_A(t + 3, 0); }
    __builtin_amdgcn_s_barrier();
    QUAD(4, 0);
    if (s3) asm volatile("s_waitcnt vmcnt(6)" ::: "memory");
    else    asm volatile("s_waitcnt vmcnt(0)" ::: "memory");
    __builtin_amdgcn_s_barrier();
  }
#undef STAGE_A
#undef STAGE_B
#undef RD_A
#undef RD_B2
#undef QUAD
#undef LGKM0

  // epilogue: C/D frag layout col=lr, row=g*4+r  [m89]
#pragma unroll
  for (int mf = 0; mf < 8; ++mf)
#pragma unroll
    for (int nf = 0; nf < 4; ++nf)
#pragma unroll
      for (int r = 0; r < 4; ++r) {
        long row = m0 + wr * 128 + mf * 16 + g * 4 + r;
        long col = n0 + wc * 64 + nf * 16 + lr;
        float v = acc[mf][nf][r];
        if constexpr (EPI == 2) {
          long i = row * N + col;
          outF[i] = v + bias[col] + res[i];
        } else if constexpr (EPI == 3) {
          outU[row * N + col] = f2bf(fmaxf(v + bias[col], 0.0f));
        } else {  // EPI 4: fused QKV
          long bb2 = row >> 8, tt = row & 255;
          long p = col >> 10, cc = col & 1023, hh = cc >> 6, e = cc & 63;
          if (p == 0)
            outU[(((bb2 * 16 + hh) * 256 + tt) << 6) + e] = f2bf(v);
          else if (p == 1)
            outU2[(((bb2 * 16 + hh) * 256 + tt) << 6) + e] = f2bf(v);
          else
            outU3[(((bb2 * 16 + hh) * 64 + e) << 8) + tt] = f2bf(v);
        }
      }
}

// ---------------- flash attention: 1 wave per (64 q rows, b, h) ------------
// q,k: [b,h,t,e] bf16; vt: [b,h,e,t] bf16; out: [b,t,h*64+e] bf16
__global__ __launch_bounds__(64) void attn_k(const ushort_t* __restrict__ q,
                                             const ushort_t* __restrict__ k,
                                             const ushort_t* __restrict__ vt,
                                             ushort_t* __restrict__ ao) {
  __shared__ __align__(16) ushort_t Ps[64][40];
  const int lane = threadIdx.x;
  const int g = lane >> 4, lr = lane & 15;
  const int blk = blockIdx.x;
  const int q4 = blk & 3;
  const int bh = blk >> 2;
  const int bb = bh >> 4, hh = bh & 15;
  const int q0 = q4 * 64;
  const ushort_t* qb = q + (long)bh * 256 * 64;
  const ushort_t* kb = k + (long)bh * 256 * 64;
  const ushort_t* vb = vt + (long)bh * 64 * 256;
  bf16x8 qf[4][2];
#pragma unroll
  for (int m = 0; m < 4; m++)
#pragma unroll
    for (int ks = 0; ks < 2; ks++)
      qf[m][ks] = *(const bf16x8*)(qb + (q0 + m * 16 + lr) * 64 + ks * 32 + g * 8);
  f32x4 o[4][4] = {};
  float mrow[4][4], lrow[4][4];
#pragma unroll
  for (int m = 0; m < 4; m++)
#pragma unroll
    for (int r = 0; r < 4; r++) { mrow[m][r] = -__builtin_inff(); lrow[m][r] = 0.0f; }
  const float scale = 0.03125f;  // 1024^-0.5
  const int nkb = q0 / 32 + 2;
  for (int kbk = 0; kbk < nkb; kbk++) {
    f32x4 s[4][2] = {};
#pragma unroll
    for (int ks = 0; ks < 2; ks++) {
      bf16x8 kf[2];
#pragma unroll
      for (int n = 0; n < 2; n++)
        kf[n] = *(const bf16x8*)(kb + (kbk * 32 + n * 16 + lr) * 64 + ks * 32 + g * 8);
#pragma unroll
      for (int m = 0; m < 4; m++)
#pragma unroll
        for (int n = 0; n < 2; n++)
          s[m][n] = __builtin_amdgcn_mfma_f32_16x16x32_bf16(qf[m][ks], kf[n], s[m][n], 0, 0, 0);
    }
#pragma unroll
    for (int m = 0; m < 4; m++)
#pragma unroll
      for (int n = 0; n < 2; n++)
#pragma unroll
        for (int r = 0; r < 4; r++) {
          int row = q0 + m * 16 + g * 4 + r;
          int col = kbk * 32 + n * 16 + lr;
          float v = s[m][n][r] * scale;
          s[m][n][r] = (col <= row) ? v : -1e30f;
        }
#pragma unroll
    for (int m = 0; m < 4; m++)
#pragma unroll
      for (int r = 0; r < 4; r++) {
        float mx = fmaxf(s[m][0][r], s[m][1][r]);
#pragma unroll
        for (int off = 8; off; off >>= 1) mx = fmaxf(mx, __shfl_xor(mx, off));
        float mn = fmaxf(mrow[m][r], mx);
        float alpha = __expf(mrow[m][r] - mn);
        mrow[m][r] = mn;
        float rs = 0.0f;
#pragma unroll
        for (int n = 0; n < 2; n++) {
          float p = __expf(s[m][n][r] - mn);
          s[m][n][r] = p;
          rs += p;
        }
#pragma unroll
        for (int off = 8; off; off >>= 1) rs += __shfl_xor(rs, off);
        lrow[m][r] = lrow[m][r] * alpha + rs;
#pragma unroll
        for (int n = 0; n < 4; n++) o[m][n][r] *= alpha;
      }
#pragma unroll
    for (int m = 0; m < 4; m++)
#pragma unroll
      for (int n = 0; n < 2; n++)
#pragma unroll
        for (int r = 0; r < 4; r++)
          Ps[m * 16 + g * 4 + r][n * 16 + lr] = f2bf(s[m][n][r]);
    __syncthreads();
    bf16x8 vf[4];
#pragma unroll
    for (int n = 0; n < 4; n++)
      vf[n] = *(const bf16x8*)(vb + (n * 16 + lr) * 256 + kbk * 32 + g * 8);
#pragma unroll
    for (int m = 0; m < 4; m++) {
      bf16x8 pa = *(const bf16x8*)&Ps[m * 16 + lr][g * 8];
#pragma unroll
      for (int n = 0; n < 4; n++)
        o[m][n] = __builtin_amdgcn_mfma_f32_16x16x32_bf16(pa, vf[n], o[m][n], 0, 0, 0);
    }
    __syncthreads();
  }
#pragma unroll
  for (int m = 0; m < 4; m++)
#pragma unroll
    for (int r = 0; r < 4; r++) {
      float inv = 1.0f / lrow[m][r];
      long t = q0 + m * 16 + g * 4 + r;
#pragma unroll
      for (int n = 0; n < 4; n++) {
        long e = n * 16 + lr;
        ao[((long)bb * 256 + t) * 1024 + hh * 64 + e] = f2bf(o[m][n][r] * inv);
      }
    }
}

// ---------------- launch ---------------------------------------------------
// Workspace map (MB offsets, 184 MB): wqt@0 wkt@2 wvt@4 (contiguous N=3072
// fused B^T) wpt@6 w1t@8 w2t@16; hb@24 (bf16 h / h2); qbf@56 kbf@88 vtb@120
// atb@152; ff1 aliases @56. fp32 residual stream lives IN d_out.
extern "C" void kernel_launch(void* const* d_in, const int* in_sizes, int n_in,
                              void* d_out, int out_size, void* d_ws, size_t ws_size,
                              hipStream_t stream) {
  const float* x     = (const float*)d_in[0];
  const float* ln1g  = (const float*)d_in[1];
  const float* ln1b  = (const float*)d_in[2];
  const float* Wq    = (const float*)d_in[3];
  const float* Wk    = (const float*)d_in[4];
  const float* Wv    = (const float*)d_in[5];
  const float* Wproj = (const float*)d_in[6];
  const float* bproj = (const float*)d_in[7];
  const float* ln2g  = (const float*)d_in[8];
  const float* ln2b  = (const float*)d_in[9];
  const float* W1    = (const float*)d_in[10];
  const float* b1    = (const float*)d_in[11];
  const float* W2    = (const float*)d_in[12];
  const float* b2    = (const float*)d_in[13];

  const long NEED = 184L << 20;
  if (ws_size < (size_t)NEED) {
    fill_k<<<(out_size + 255) / 256, 256, 0, stream>>>((float*)d_out, out_size,
                                                       (float)(ws_size >> 20));
    return;
  }

  char* ws = (char*)d_ws;
  const long MB = 1 << 20;
  ushort_t* wqt = (ushort_t*)(ws + 0 * MB);   // [0,6MB) = fused QKV B^T, N=3072
  ushort_t* wkt = (ushort_t*)(ws + 2 * MB);
  ushort_t* wvt = (ushort_t*)(ws + 4 * MB);
  ushort_t* wpt = (ushort_t*)(ws + 6 * MB);
  ushort_t* w1t = (ushort_t*)(ws + 8 * MB);
  ushort_t* w2t = (ushort_t*)(ws + 16 * MB);
  ushort_t* hb  = (ushort_t*)(ws + 24 * MB);
  ushort_t* qbf = (ushort_t*)(ws + 56 * MB);
  ushort_t* kbf = (ushort_t*)(ws + 88 * MB);
  ushort_t* vtb = (ushort_t*)(ws + 120 * MB);
  ushort_t* atb = (ushort_t*)(ws + 152 * MB);
  ushort_t* ff1 = (ushort_t*)(ws + 56 * MB);
  float*    yf  = (float*)d_out;

  transpose_w<<<dim3(32, 2, 16), 256, 0, stream>>>(Wq, wqt, 1024, 64);
  transpose_w<<<dim3(32, 2, 16), 256, 0, stream>>>(Wk, wkt, 1024, 64);
  transpose_w<<<dim3(32, 2, 16), 256, 0, stream>>>(Wv, wvt, 1024, 64);
  transpose_w<<<dim3(32, 32, 1), 256, 0, stream>>>(Wproj, wpt, 1024, 1024);
  transpose_w<<<dim3(32, 128, 1), 256, 0, stream>>>(W1, w1t, 1024, 4096);
  transpose_w<<<dim3(128, 32, 1), 256, 0, stream>>>(W2, w2t, 4096, 1024);

  ln_k<<<16384, 256, 0, stream>>>(x, ln1g, ln1b, yf, hb);
  // fused q/k/v projection (M=16384, N=3072, K=1024; grid 64x12=768)
  gemm256<4><<<768, 512, 0, stream>>>(hb, wqt, 16384, 3072, 1024, 12,
                                      nullptr, nullptr, nullptr, qbf, kbf, vtb);
  attn_k<<<4096, 64, 0, stream>>>(qbf, kbf, vtb, atb);
  // y = h + attn @ Wproj + bproj
  gemm256<2><<<256, 512, 0, stream>>>(atb, wpt, 16384, 1024, 1024, 4,
                                      bproj, yf, yf, nullptr, nullptr, nullptr);
  ln_k<<<16384, 256, 0, stream>>>(yf, ln2g, ln2b, yf, hb);
  // ff1 = relu(h2 @ W1 + b1)  (N=4096; grid 64x16=1024)
  gemm256<3><<<1024, 512, 0, stream>>>(hb, w1t, 16384, 4096, 1024, 16,
                                       b1, nullptr, nullptr, ff1, nullptr, nullptr);
  // out = h2 + ff1 @ W2 + b2  (K=4096)
  gemm256<2><<<256, 512, 0, stream>>>(ff1, w2t, 16384, 1024, 4096, 4,
                                      b2, yf, yf, nullptr, nullptr, nullptr);
}

// Round 7
// 635.193 us; speedup vs baseline: 1.0911x; 1.0816x over previous
//
#include <hip/hip_runtime.h>

typedef __bf16 bf16x8 __attribute__((ext_vector_type(8)));
typedef float f32x4 __attribute__((ext_vector_type(4)));
typedef unsigned short ushort_t;

__device__ __forceinline__ ushort_t f2bf(float f) {
  unsigned int u = __float_as_uint(f);
  u += 0x7fffu + ((u >> 16) & 1u);
  return (ushort_t)(u >> 16);
}

// async global->LDS, 16 bytes per lane (dest = wave-uniform base + lane*16)
__device__ __forceinline__ void gl_lds16(const ushort_t* g, const char* l) {
  __builtin_amdgcn_global_load_lds(
      (const __attribute__((address_space(1))) void*)g,
      (__attribute__((address_space(3))) void*)l, 16, 0, 0);
}

__global__ __launch_bounds__(256) void fill_k(float* __restrict__ p, long n, float v) {
  long i = (long)blockIdx.x * 256 + threadIdx.x;
  if (i < n) p[i] = v;
}

// ---------------- batched transpose: fp32 Z x R x C  ->  bf16 Z x C x R ----
__global__ __launch_bounds__(256) void transpose_w(const float* __restrict__ in,
                                                   ushort_t* __restrict__ out,
                                                   int R, int C) {
  __shared__ float tile[32][33];
  const float* inb = in + (long)blockIdx.z * R * C;
  ushort_t* outb = out + (long)blockIdx.z * R * C;
  int r0 = blockIdx.x * 32, c0 = blockIdx.y * 32;
  int tx = threadIdx.x & 31, ty = threadIdx.x >> 5;
#pragma unroll
  for (int i = ty; i < 32; i += 8) tile[i][tx] = inb[(long)(r0 + i) * C + (c0 + tx)];
  __syncthreads();
#pragma unroll
  for (int i = ty; i < 32; i += 8) outb[(long)(c0 + i) * R + (r0 + tx)] = f2bf(tile[tx][i]);
}

// ---------------- layernorm: one row (D=1024) per 256-thread block ---------
__global__ __launch_bounds__(256) void ln_k(const float* __restrict__ x,
                                            const float* __restrict__ g,
                                            const float* __restrict__ b,
                                            float* __restrict__ outF,
                                            ushort_t* __restrict__ outU) {
  __shared__ float red[8];
  long row = blockIdx.x;
  int tid = threadIdx.x;
  float4 v = ((const float4*)(x + row * 1024))[tid];
  float s = v.x + v.y + v.z + v.w;
#pragma unroll
  for (int off = 32; off; off >>= 1) s += __shfl_xor(s, off);
  int w = tid >> 6;
  if ((tid & 63) == 0) red[w] = s;
  __syncthreads();
  float mean = (red[0] + red[1] + red[2] + red[3]) * (1.0f / 1024.0f);
  float dx = v.x - mean, dy = v.y - mean, dz = v.z - mean, dw = v.w - mean;
  float s2 = dx * dx + dy * dy + dz * dz + dw * dw;
#pragma unroll
  for (int off = 32; off; off >>= 1) s2 += __shfl_xor(s2, off);
  if ((tid & 63) == 0) red[4 + w] = s2;
  __syncthreads();
  float var = (red[4] + red[5] + red[6] + red[7]) * (1.0f / 1024.0f);
  float rstd = rsqrtf(var + 1e-5f);
  int c = tid * 4;
  float o0 = dx * rstd * g[c + 0] + b[c + 0];
  float o1 = dy * rstd * g[c + 1] + b[c + 1];
  float o2 = dz * rstd * g[c + 2] + b[c + 2];
  float o3 = dw * rstd * g[c + 3] + b[c + 3];
  ((float4*)(outF + row * 1024))[tid] = make_float4(o0, o1, o2, o3);
  ushort4 u;
  u.x = f2bf(o0); u.y = f2bf(o1); u.z = f2bf(o2); u.w = f2bf(o3);
  ((ushort4*)(outU + row * 1024))[tid] = u;
}

// ---------------- 256x256 8-wave 8-phase bf16 GEMM (BK=64, m201 rhythm) ----
// Identical K-loop to round 6. Epilogues:
//  2: fp32 acc+bias[col]+res   3: bf16 relu(acc+bias[col])
//  4: fused QKV -> q[b,h,t,e], k[b,h,t,e], v[b,h,e,t].
//     V third now transposes through LDS (dead after K-loop) so vt stores are
//     contiguous 512B runs instead of stride-256 2B scatter.
template <int EPI>
__global__ __launch_bounds__(512, 2) void gemm256(const ushort_t* __restrict__ A,
                                                  const ushort_t* __restrict__ Bt,
                                                  int M, int N, int K, int NBC,
                                                  const float* __restrict__ bias,
                                                  const float* res, float* outF,
                                                  ushort_t* __restrict__ outU,
                                                  ushort_t* __restrict__ outU2,
                                                  ushort_t* __restrict__ outU3) {
  __shared__ __align__(16) char lds[131072];
  const int tid = threadIdx.x;
  const int lane = tid & 63;
  const int w = tid >> 6;            // 0..7
  const int wr = w >> 2, wc = w & 3; // 2 x 4 wave grid
  const int g = lane >> 4, lr = lane & 15;
  const int cpx = gridDim.x >> 3;
  const int wg = (blockIdx.x & 7) * cpx + (blockIdx.x >> 3);
  const long m0 = (long)(wg / NBC) * 256;
  const long n0 = (long)(wg % NBC) * 256;
  // staging source (pre-swizzled so linear gl_lds dest yields swizzled LDS)
  const int srow = tid >> 3;                  // 0..63 within an 8KB issue
  const int sslot = (tid & 7) ^ (srow & 7);   // logical 16B slot to fetch
  const ushort_t* sA = A + (m0 + srow) * (long)K + sslot * 8;
  const ushort_t* sB = Bt + (n0 + srow) * (long)K + sslot * 8;
  const int dA = tid * 16;
  const int dB = 32768 + tid * 16;
  // ds_read bases: row-major [256][64]x2B per region, phys slot = log^(row&7)
  const int abase = (wr * 128 + lr) * 128;
  const int bbase = 32768 + (wc * 64 + lr) * 128;
  const int s0 = g ^ (lr & 7);         // ks=0: logical slot g
  const int s1 = (4 + g) ^ (lr & 7);   // ks=1: logical slot 4+g
  const int NT = K >> 6;

  f32x4 acc[8][4] = {};
  bf16x8 aR[4][2], bR[4][2];
  const char* rb;

#define STAGE_A(tile, half) do {                                          \
    const long _ko = (long)(tile) * 64;                                   \
    char* _d = lds + (((tile) & 1) << 16) + ((half) << 14) + dA;          \
    gl_lds16(sA + _ko + (long)(2 * (half)) * 64 * K, _d);                 \
    gl_lds16(sA + _ko + (long)(2 * (half) + 1) * 64 * K, _d + 8192);      \
  } while (0)
#define STAGE_B(tile, half) do {                                          \
    const long _ko = (long)(tile) * 64;                                   \
    char* _d = lds + (((tile) & 1) << 16) + ((half) << 14) + dB;          \
    gl_lds16(sB + _ko + (long)(2 * (half)) * 64 * K, _d);                 \
    gl_lds16(sB + _ko + (long)(2 * (half) + 1) * 64 * K, _d + 8192);      \
  } while (0)
#define RD_A(base_mf) do {                                                \
    _Pragma("unroll") for (int mf = 0; mf < 4; ++mf) {                    \
      aR[mf][0] = *(const bf16x8*)(rb + abase + ((base_mf) + mf) * 2048 + s0 * 16); \
      aR[mf][1] = *(const bf16x8*)(rb + abase + ((base_mf) + mf) * 2048 + s1 * 16); \
    } } while (0)
#define RD_B2(base_nf) do {                                               \
    _Pragma("unroll") for (int nf = 0; nf < 2; ++nf) {                    \
      bR[(base_nf) + nf][0] = *(const bf16x8*)(rb + bbase + ((base_nf) + nf) * 2048 + s0 * 16); \
      bR[(base_nf) + nf][1] = *(const bf16x8*)(rb + bbase + ((base_nf) + nf) * 2048 + s1 * 16); \
    } } while (0)
#define QUAD(MB, NB) do {                                                 \
    __builtin_amdgcn_s_setprio(1);                                        \
    _Pragma("unroll") for (int mf = 0; mf < 4; ++mf)                      \
      _Pragma("unroll") for (int nf = 0; nf < 2; ++nf) {                  \
        acc[(MB) + mf][(NB) + nf] = __builtin_amdgcn_mfma_f32_16x16x32_bf16(aR[mf][0], bR[(NB) + nf][0], acc[(MB) + mf][(NB) + nf], 0, 0, 0); \
        acc[(MB) + mf][(NB) + nf] = __builtin_amdgcn_mfma_f32_16x16x32_bf16(aR[mf][1], bR[(NB) + nf][1], acc[(MB) + mf][(NB) + nf], 0, 0, 0); \
      }                                                                   \
    __builtin_amdgcn_s_setprio(0); } while (0)
#define LGKM0 do {                                                        \
    asm volatile("s_waitcnt lgkmcnt(0)" ::: "memory");                    \
    __builtin_amdgcn_sched_barrier(0); } while (0)

  // ---- prologue: 7 half-tiles, oldest-first; drain tile 0 (8 loads) ----
  STAGE_B(0, 0); STAGE_B(0, 1); STAGE_A(0, 0); STAGE_A(0, 1);
  STAGE_B(1, 0); STAGE_B(1, 1); STAGE_A(1, 0);
  asm volatile("s_waitcnt vmcnt(6)" ::: "memory");
  __builtin_amdgcn_s_barrier();

  for (int t = 0; t < NT; t += 2) {
    const bool s2 = (t + 2 < NT), s3 = (t + 3 < NT);
    // ===================== tile t (buf0) =====================
    rb = lds;
    RD_A(0);
    RD_B2(0);
    STAGE_A(t + 1, 1);
    asm volatile("s_waitcnt lgkmcnt(8)" ::: "memory");
    __builtin_amdgcn_s_barrier();
    LGKM0;
    QUAD(0, 0);
    __builtin_amdgcn_s_barrier();
    RD_B2(2);
    __builtin_amdgcn_s_barrier();
    LGKM0;
    QUAD(0, 2);
    __builtin_amdgcn_s_barrier();
    if (s2) STAGE_B(t + 2, 0);
    RD_A(4);
    __builtin_amdgcn_s_barrier();
    LGKM0;
    QUAD(4, 2);
    __builtin_amdgcn_s_barrier();
    if (s2) { STAGE_B(t + 2, 1); STAGE_A(t + 2, 0); }
    __builtin_amdgcn_s_barrier();
    QUAD(4, 0);
    if (s2) asm volatile("s_waitcnt vmcnt(6)" ::: "memory");
    else    asm volatile("s_waitcnt vmcnt(0)" ::: "memory");
    __builtin_amdgcn_s_barrier();
    // ===================== tile t+1 (buf1) =====================
    rb = lds + 65536;
    RD_A(0);
    RD_B2(0);
    if (s2) STAGE_A(t + 2, 1);
    asm volatile("s_waitcnt lgkmcnt(8)" ::: "memory");
    __builtin_amdgcn_s_barrier();
    LGKM0;
    QUAD(0, 0);
    __builtin_amdgcn_s_barrier();
    RD_B2(2);
    __builtin_amdgcn_s_barrier();
    LGKM0;
    QUAD(0, 2);
    __builtin_amdgcn_s_barrier();
    if (s3) STAGE_B(t + 3, 0);
    RD_A(4);
    __builtin_amdgcn_s_barrier();
    LGKM0;
    QUAD(4, 2);
    __builtin_amdgcn_s_barrier();
    if (s3) { STAGE_B(t + 3, 1); STAGE_A(t + 3, 0); }
    __builtin_amdgcn_s_barrier();
    QUAD(4, 0);
    if (s3) asm volatile("s_waitcnt vmcnt(6)" ::: "memory");
    else    asm volatile("s_waitcnt vmcnt(0)" ::: "memory");
    __builtin_amdgcn_s_barrier();
  }
#undef STAGE_A
#undef STAGE_B
#undef RD_A
#undef RD_B2
#undef QUAD
#undef LGKM0

  // epilogue: C/D frag layout col=lr, row=g*4+r  [m89]
  if constexpr (EPI == 4) {
    const int p = (int)(n0 >> 10);       // block-uniform: which of q/k/v
    const long bb2 = m0 >> 8;
    if (p < 2) {
      ushort_t* dst = (p == 0) ? outU : outU2;
#pragma unroll
      for (int mf = 0; mf < 8; ++mf)
#pragma unroll
        for (int nf = 0; nf < 4; ++nf)
#pragma unroll
          for (int r = 0; r < 4; ++r) {
            long tt = (wr * 128 + mf * 16 + g * 4 + r);
            long cc = (n0 & 1023) + wc * 64 + nf * 16 + lr;
            long hh = cc >> 6, e = cc & 63;
            dst[(((bb2 * 16 + hh) * 256 + tt) << 6) + e] = f2bf(acc[mf][nf][r]);
          }
    } else {
      // V third: transpose 256x256 tile through LDS, then coalesced stores.
      unsigned int* l32 = (unsigned int*)lds;
#pragma unroll
      for (int mf = 0; mf < 8; ++mf)
#pragma unroll
        for (int nf = 0; nf < 4; ++nf)
#pragma unroll
          for (int r2 = 0; r2 < 2; ++r2) {
            int row = wr * 128 + mf * 16 + g * 4 + r2 * 2;  // local tt (even)
            int col = wc * 64 + nf * 16 + lr;               // local v-col
            unsigned int pk = (unsigned int)f2bf(acc[mf][nf][r2 * 2]) |
                              ((unsigned int)f2bf(acc[mf][nf][r2 * 2 + 1]) << 16);
            l32[col * 128 + ((row >> 1) ^ ((col & 7) << 2))] = pk;
          }
      __syncthreads();
      const long vcol0 = (n0 & 1023);
#pragma unroll
      for (int k = 0; k < 16; ++k) {
        int c = tid + k * 512;           // 8192 16B-chunks total
        int e_l = c >> 5, k16 = c & 31;  // e-row, chunk within 512B row
        uint4 d = *(uint4*)&l32[e_l * 128 + ((k16 * 4) ^ ((e_l & 7) << 2))];
        long vc = vcol0 + e_l;
        long hh = vc >> 6, e = vc & 63;
        *(uint4*)&outU3[(((bb2 * 16 + hh) * 64 + e) << 8) + k16 * 8] = d;
      }
    }
  } else {
#pragma unroll
    for (int mf = 0; mf < 8; ++mf)
#pragma unroll
      for (int nf = 0; nf < 4; ++nf)
#pragma unroll
        for (int r = 0; r < 4; ++r) {
          long row = m0 + wr * 128 + mf * 16 + g * 4 + r;
          long col = n0 + wc * 64 + nf * 16 + lr;
          float v = acc[mf][nf][r];
          if constexpr (EPI == 2) {
            long i = row * N + col;
            outF[i] = v + bias[col] + res[i];
          } else {
            outU[row * N + col] = f2bf(fmaxf(v + bias[col], 0.0f));
          }
        }
  }
}

// ---------------- flash attention: 1 wave per (64 q rows, b, h) ------------
// q,k: [b,h,t,e] bf16; vt: [b,h,e,t] bf16; out: [b,t,h*64+e] bf16
__global__ __launch_bounds__(64) void attn_k(const ushort_t* __restrict__ q,
                                             const ushort_t* __restrict__ k,
                                             const ushort_t* __restrict__ vt,
                                             ushort_t* __restrict__ ao) {
  __shared__ __align__(16) ushort_t Ps[64][40];
  const int lane = threadIdx.x;
  const int g = lane >> 4, lr = lane & 15;
  const int blk = blockIdx.x;
  const int q4 = blk & 3;
  const int bh = blk >> 2;
  const int bb = bh >> 4, hh = bh & 15;
  const int q0 = q4 * 64;
  const ushort_t* qb = q + (long)bh * 256 * 64;
  const ushort_t* kb = k + (long)bh * 256 * 64;
  const ushort_t* vb = vt + (long)bh * 64 * 256;
  bf16x8 qf[4][2];
#pragma unroll
  for (int m = 0; m < 4; m++)
#pragma unroll
    for (int ks = 0; ks < 2; ks++)
      qf[m][ks] = *(const bf16x8*)(qb + (q0 + m * 16 + lr) * 64 + ks * 32 + g * 8);
  f32x4 o[4][4] = {};
  float mrow[4][4], lrow[4][4];
#pragma unroll
  for (int m = 0; m < 4; m++)
#pragma unroll
    for (int r = 0; r < 4; r++) { mrow[m][r] = -__builtin_inff(); lrow[m][r] = 0.0f; }
  const float scale = 0.03125f;  // 1024^-0.5
  const int nkb = q0 / 32 + 2;
  for (int kbk = 0; kbk < nkb; kbk++) {
    f32x4 s[4][2] = {};
#pragma unroll
    for (int ks = 0; ks < 2; ks++) {
      bf16x8 kf[2];
#pragma unroll
      for (int n = 0; n < 2; n++)
        kf[n] = *(const bf16x8*)(kb + (kbk * 32 + n * 16 + lr) * 64 + ks * 32 + g * 8);
#pragma unroll
      for (int m = 0; m < 4; m++)
#pragma unroll
        for (int n = 0; n < 2; n++)
          s[m][n] = __builtin_amdgcn_mfma_f32_16x16x32_bf16(qf[m][ks], kf[n], s[m][n], 0, 0, 0);
    }
#pragma unroll
    for (int m = 0; m < 4; m++)
#pragma unroll
      for (int n = 0; n < 2; n++)
#pragma unroll
        for (int r = 0; r < 4; r++) {
          int row = q0 + m * 16 + g * 4 + r;
          int col = kbk * 32 + n * 16 + lr;
          float v = s[m][n][r] * scale;
          s[m][n][r] = (col <= row) ? v : -1e30f;
        }
#pragma unroll
    for (int m = 0; m < 4; m++)
#pragma unroll
      for (int r = 0; r < 4; r++) {
        float mx = fmaxf(s[m][0][r], s[m][1][r]);
#pragma unroll
        for (int off = 8; off; off >>= 1) mx = fmaxf(mx, __shfl_xor(mx, off));
        float mn = fmaxf(mrow[m][r], mx);
        float alpha = __expf(mrow[m][r] - mn);
        mrow[m][r] = mn;
        float rs = 0.0f;
#pragma unroll
        for (int n = 0; n < 2; n++) {
          float p = __expf(s[m][n][r] - mn);
          s[m][n][r] = p;
          rs += p;
        }
#pragma unroll
        for (int off = 8; off; off >>= 1) rs += __shfl_xor(rs, off);
        lrow[m][r] = lrow[m][r] * alpha + rs;
#pragma unroll
        for (int n = 0; n < 4; n++) o[m][n][r] *= alpha;
      }
#pragma unroll
    for (int m = 0; m < 4; m++)
#pragma unroll
      for (int n = 0; n < 2; n++)
#pragma unroll
        for (int r = 0; r < 4; r++)
          Ps[m * 16 + g * 4 + r][n * 16 + lr] = f2bf(s[m][n][r]);
    __syncthreads();
    bf16x8 vf[4];
#pragma unroll
    for (int n = 0; n < 4; n++)
      vf[n] = *(const bf16x8*)(vb + (n * 16 + lr) * 256 + kbk * 32 + g * 8);
#pragma unroll
    for (int m = 0; m < 4; m++) {
      bf16x8 pa = *(const bf16x8*)&Ps[m * 16 + lr][g * 8];
#pragma unroll
      for (int n = 0; n < 4; n++)
        o[m][n] = __builtin_amdgcn_mfma_f32_16x16x32_bf16(pa, vf[n], o[m][n], 0, 0, 0);
    }
    __syncthreads();
  }
#pragma unroll
  for (int m = 0; m < 4; m++)
#pragma unroll
    for (int r = 0; r < 4; r++) {
      float inv = 1.0f / lrow[m][r];
      long t = q0 + m * 16 + g * 4 + r;
#pragma unroll
      for (int n = 0; n < 4; n++) {
        long e = n * 16 + lr;
        ao[((long)bb * 256 + t) * 1024 + hh * 64 + e] = f2bf(o[m][n][r] * inv);
      }
    }
}

// ---------------- launch ---------------------------------------------------
// Workspace map (MB offsets, 184 MB): wqt@0 wkt@2 wvt@4 (contiguous N=3072
// fused B^T) wpt@6 w1t@8 w2t@16; hb@24 (bf16 h / h2); qbf@56 kbf@88 vtb@120
// atb@152; ff1 aliases @56. fp32 residual stream lives IN d_out.
extern "C" void kernel_launch(void* const* d_in, const int* in_sizes, int n_in,
                              void* d_out, int out_size, void* d_ws, size_t ws_size,
                              hipStream_t stream) {
  const float* x     = (const float*)d_in[0];
  const float* ln1g  = (const float*)d_in[1];
  const float* ln1b  = (const float*)d_in[2];
  const float* Wq    = (const float*)d_in[3];
  const float* Wk    = (const float*)d_in[4];
  const float* Wv    = (const float*)d_in[5];
  const float* Wproj = (const float*)d_in[6];
  const float* bproj = (const float*)d_in[7];
  const float* ln2g  = (const float*)d_in[8];
  const float* ln2b  = (const float*)d_in[9];
  const float* W1    = (const float*)d_in[10];
  const float* b1    = (const float*)d_in[11];
  const float* W2    = (const float*)d_in[12];
  const float* b2    = (const float*)d_in[13];

  const long NEED = 184L << 20;
  if (ws_size < (size_t)NEED) {
    fill_k<<<(out_size + 255) / 256, 256, 0, stream>>>((float*)d_out, out_size,
                                                       (float)(ws_size >> 20));
    return;
  }

  char* ws = (char*)d_ws;
  const long MB = 1 << 20;
  ushort_t* wqt = (ushort_t*)(ws + 0 * MB);   // [0,6MB) = fused QKV B^T, N=3072
  ushort_t* wkt = (ushort_t*)(ws + 2 * MB);
  ushort_t* wvt = (ushort_t*)(ws + 4 * MB);
  ushort_t* wpt = (ushort_t*)(ws + 6 * MB);
  ushort_t* w1t = (ushort_t*)(ws + 8 * MB);
  ushort_t* w2t = (ushort_t*)(ws + 16 * MB);
  ushort_t* hb  = (ushort_t*)(ws + 24 * MB);
  ushort_t* qbf = (ushort_t*)(ws + 56 * MB);
  ushort_t* kbf = (ushort_t*)(ws + 88 * MB);
  ushort_t* vtb = (ushort_t*)(ws + 120 * MB);
  ushort_t* atb = (ushort_t*)(ws + 152 * MB);
  ushort_t* ff1 = (ushort_t*)(ws + 56 * MB);
  float*    yf  = (float*)d_out;

  transpose_w<<<dim3(32, 2, 16), 256, 0, stream>>>(Wq, wqt, 1024, 64);
  transpose_w<<<dim3(32, 2, 16), 256, 0, stream>>>(Wk, wkt, 1024, 64);
  transpose_w<<<dim3(32, 2, 16), 256, 0, stream>>>(Wv, wvt, 1024, 64);
  transpose_w<<<dim3(32, 32, 1), 256, 0, stream>>>(Wproj, wpt, 1024, 1024);
  transpose_w<<<dim3(32, 128, 1), 256, 0, stream>>>(W1, w1t, 1024, 4096);
  transpose_w<<<dim3(128, 32, 1), 256, 0, stream>>>(W2, w2t, 4096, 1024);

  ln_k<<<16384, 256, 0, stream>>>(x, ln1g, ln1b, yf, hb);
  // fused q/k/v projection (M=16384, N=3072, K=1024; grid 64x12=768)
  gemm256<4><<<768, 512, 0, stream>>>(hb, wqt, 16384, 3072, 1024, 12,
                                      nullptr, nullptr, nullptr, qbf, kbf, vtb);
  attn_k<<<4096, 64, 0, stream>>>(qbf, kbf, vtb, atb);
  // y = h + attn @ Wproj + bproj
  gemm256<2><<<256, 512, 0, stream>>>(atb, wpt, 16384, 1024, 1024, 4,
                                      bproj, yf, yf, nullptr, nullptr, nullptr);
  ln_k<<<16384, 256, 0, stream>>>(yf, ln2g, ln2b, yf, hb);
  // ff1 = relu(h2 @ W1 + b1)  (N=4096; grid 64x16=1024)
  gemm256<3><<<1024, 512, 0, stream>>>(hb, w1t, 16384, 4096, 1024, 16,
                                       b1, nullptr, nullptr, ff1, nullptr, nullptr);
  // out = h2 + ff1 @ W2 + b2  (K=4096)
  gemm256<2><<<256, 512, 0, stream>>>(ff1, w2t, 16384, 1024, 4096, 4,
                                      b2, yf, yf, nullptr, nullptr, nullptr);
}